// Round 1
// baseline (739.576 us; speedup 1.0000x reference)
//
#include <hip/hip_runtime.h>
#include <hip/hip_bf16.h>

#define NN 100000
#define NE 300000
#define NG 2000
#define DD 256
#define NL 5
#define BN_EPS 1e-5f

typedef __bf16 bf16x8 __attribute__((ext_vector_type(8)));
typedef float floatx16 __attribute__((ext_vector_type(16)));

__device__ inline unsigned short f2bf(float x) {
  unsigned int u = __builtin_bit_cast(unsigned int, x);
  unsigned int r = u + 0x7FFFu + ((u >> 16) & 1u);
  return (unsigned short)(r >> 16);
}
__device__ inline float bf2f(unsigned short u) {
  return __builtin_bit_cast(float, (unsigned int)u << 16);
}
__device__ inline float4 bfu4(ushort4 u) {
  return make_float4(bf2f(u.x), bf2f(u.y), bf2f(u.z), bf2f(u.w));
}
__device__ inline float blo(unsigned int v) {
  return __builtin_bit_cast(float, v << 16);
}
__device__ inline float bhi(unsigned int v) {
  return __builtin_bit_cast(float, v & 0xFFFF0000u);
}
__device__ inline unsigned int pack2(float a, float b) {
  return (unsigned int)f2bf(a) | ((unsigned int)f2bf(b) << 16);
}

// ---------------- utility ----------------
__global__ __launch_bounds__(256) void k_zeroi(int* __restrict__ p, int n) {
  int i = blockIdx.x * 256 + threadIdx.x;
  if (i < n) p[i] = 0;
}

// ---------------- weight pack (18 matrices) + vn init, one dispatch ----------------
__global__ __launch_bounds__(256) void k_pack_all(
    const float* __restrict__ gw1, const float* __restrict__ gw2,
    const float* __restrict__ vw1, const float* __restrict__ vw2,
    unsigned short* __restrict__ Wf,
    const float* __restrict__ vnw, unsigned short* __restrict__ vnb) {
  int idx = blockIdx.x * 256 + threadIdx.x;
  if (idx >= 18 * 65536) {
    int i = idx - 18 * 65536;
    if (i < NG * DD) vnb[i] = f2bf(vnw[i & (DD - 1)]);
    return;
  }
  int m = idx >> 16, r = idx & 65535;
  int j = r & 7, lane = (r >> 3) & 63, ks = (r >> 9) & 15, nt = r >> 13;
  int n = nt * 32 + (lane & 31);
  int k = ks * 16 + ((lane >> 5) << 3) + j;
  const float* W;
  int mm;
  if (m < 5) { W = gw1; mm = m; }
  else if (m < 10) { W = gw2; mm = m - 5; }
  else if (m < 14) { W = vw1; mm = m - 10; }
  else { W = vw2; mm = m - 14; }
  Wf[idx] = f2bf(W[(size_t)mm * 65536 + k * 256 + n]);
}

// ---------------- CSR build ----------------
__global__ __launch_bounds__(256) void k_hist(const int* __restrict__ dst,
                                              int* __restrict__ cnt) {
  int e = blockIdx.x * 256 + threadIdx.x;
  if (e < NE) atomicAdd(&cnt[dst[e]], 1);
}

__global__ __launch_bounds__(1024) void k_bsum(const int* __restrict__ cnt,
                                               int* __restrict__ bsum) {
  __shared__ int sh[1024];
  int t = threadIdx.x, idx = blockIdx.x * 1024 + t;
  sh[t] = (idx < NN) ? cnt[idx] : 0;
  __syncthreads();
  for (int off = 512; off > 0; off >>= 1) {
    if (t < off) sh[t] += sh[t + off];
    __syncthreads();
  }
  if (t == 0) bsum[blockIdx.x] = sh[0];
}

__global__ __launch_bounds__(128) void k_scanb(const int* __restrict__ bsum,
                                               int* __restrict__ bbase, int nb) {
  __shared__ int sh[128];
  int t = threadIdx.x;
  sh[t] = (t < nb) ? bsum[t] : 0;
  __syncthreads();
  if (t == 0) {
    int run = 0;
    for (int i = 0; i < nb; ++i) { int v = sh[i]; sh[i] = run; run += v; }
  }
  __syncthreads();
  if (t < nb) bbase[t] = sh[t];
}

__global__ __launch_bounds__(1024) void k_rowptr(const int* __restrict__ cnt,
                                                 const int* __restrict__ bbase,
                                                 int* __restrict__ rowptr,
                                                 int* __restrict__ cursor) {
  __shared__ int sh[1024];
  int t = threadIdx.x, idx = blockIdx.x * 1024 + t;
  int v = (idx < NN) ? cnt[idx] : 0;
  sh[t] = v;
  __syncthreads();
  for (int off = 1; off < 1024; off <<= 1) {
    int add = (t >= off) ? sh[t - off] : 0;
    __syncthreads();
    sh[t] += add;
    __syncthreads();
  }
  if (idx < NN) {
    int excl = sh[t] - v + bbase[blockIdx.x];
    rowptr[idx] = excl;
    cursor[idx] = excl;
  }
  if (blockIdx.x == 0 && t == 0) rowptr[NN] = NE;
}

__global__ __launch_bounds__(256) void k_fill_src(const int* __restrict__ src,
                                                  const int* __restrict__ dst,
                                                  int* __restrict__ cursor,
                                                  int* __restrict__ ssrc) {
  int e = blockIdx.x * 256 + threadIdx.x;
  if (e >= NE) return;
  int pos = atomicAdd(&cursor[dst[e]], 1);
  ssrc[pos] = src[e];
}

// ---------------- graph bounds from sorted batch (no atomics) ----------------
__global__ __launch_bounds__(256) void k_gbounds(const int* __restrict__ batch,
                                                 int* __restrict__ gstart,
                                                 int* __restrict__ gend) {
  int n = blockIdx.x * 256 + threadIdx.x;
  if (n >= NN) return;
  int b = batch[n];
  if (n == 0 || batch[n - 1] != b) gstart[b] = n;
  if (n == NN - 1 || batch[n + 1] != b) gend[b] = n + 1;
}

// ---------------- node encode -> bf16 (16 nodes/block, w in LDS) ----------------
__global__ __launch_bounds__(256) void k_node_encode(
    const float* __restrict__ x, const float* __restrict__ w,
    const float* __restrict__ b, unsigned short* __restrict__ h16) {
  __shared__ float ws[20][256];
  __shared__ float xr[16][20];
  int tid = threadIdx.x;
  int n0 = blockIdx.x * 16;
  for (int p = tid; p < 20 * 64; p += 256) {
    int k = p >> 6, c4 = (p & 63) << 2;
    *(float4*)&ws[k][c4] = *(const float4*)(w + k * 256 + c4);
  }
  for (int p = tid; p < 320; p += 256) {
    int nn = p / 20, k = p - nn * 20;
    xr[nn][k] = x[(size_t)(n0 + nn) * 20 + k];
  }
  __syncthreads();
  int ln = tid >> 6, c4 = (tid & 63) << 2;
  float4 bv = *(const float4*)(b + c4);
  float a[4][4];
#pragma unroll
  for (int nn = 0; nn < 4; ++nn) {
    a[nn][0] = bv.x; a[nn][1] = bv.y; a[nn][2] = bv.z; a[nn][3] = bv.w;
  }
#pragma unroll
  for (int k = 0; k < 20; ++k) {
    float4 wv = *(float4*)&ws[k][c4];
#pragma unroll
    for (int nn = 0; nn < 4; ++nn) {
      float xv = xr[ln * 4 + nn][k];
      a[nn][0] = fmaf(xv, wv.x, a[nn][0]);
      a[nn][1] = fmaf(xv, wv.y, a[nn][1]);
      a[nn][2] = fmaf(xv, wv.z, a[nn][2]);
      a[nn][3] = fmaf(xv, wv.w, a[nn][3]);
    }
  }
#pragma unroll
  for (int nn = 0; nn < 4; ++nn) {
    int n = n0 + ln * 4 + nn;
    *(ushort4*)(h16 + (size_t)n * DD + c4) =
        make_ushort4(f2bf(a[nn][0]), f2bf(a[nn][1]), f2bf(a[nn][2]), f2bf(a[nn][3]));
  }
}

// ---------------- segment pool: one block per graph, no atomics ----------------
template <int MODE>
__global__ __launch_bounds__(256) void k_pool_seg(
    const unsigned short* __restrict__ h16, const unsigned short* __restrict__ vnb,
    const int* __restrict__ gstart, const int* __restrict__ gend,
    unsigned short* __restrict__ outb, float* __restrict__ outf) {
  __shared__ float4 sh[4][64];
  int g = blockIdx.x;
  int lane = threadIdx.x & 63, grp = threadIdx.x >> 6;
  int c4 = lane << 2;
  int s = gstart[g], e = gend[g];
  float4 acc = make_float4(0.f, 0.f, 0.f, 0.f);
  for (int n = s + grp; n < e; n += 4) {
    float4 v = bfu4(*(const ushort4*)(h16 + (size_t)n * DD + c4));
    acc.x += v.x; acc.y += v.y; acc.z += v.z; acc.w += v.w;
  }
  sh[grp][lane] = acc;
  __syncthreads();
  if (grp == 0) {
    float4 a0 = sh[0][lane], a1 = sh[1][lane], a2 = sh[2][lane], a3 = sh[3][lane];
    acc.x = a0.x + a1.x + a2.x + a3.x;
    acc.y = a0.y + a1.y + a2.y + a3.y;
    acc.z = a0.z + a1.z + a2.z + a3.z;
    acc.w = a0.w + a1.w + a2.w + a3.w;
    if (MODE == 0) {
      float4 v = bfu4(*(const ushort4*)(vnb + (size_t)g * DD + c4));
      acc.x += v.x; acc.y += v.y; acc.z += v.z; acc.w += v.w;
      *(ushort4*)(outb + (size_t)g * DD + c4) =
          make_ushort4(f2bf(acc.x), f2bf(acc.y), f2bf(acc.z), f2bf(acc.w));
    } else {
      *(float4*)(outf + (size_t)g * DD + c4) = acc;
    }
  }
}

// ---------------- fused GIN layer (512 threads, 64 rows/block) ----------------
// Gather fuses the +vn[batch] add (kills the u16 round-trip kernel).
// 8 threads/row, thread q owns cols {16q..16q+15} U {128+16q..+15} so its LDS
// fragment stores hit ks = q and q+8 (bank-group = r^q, a Latin square ->
// conflict-free). Each wave computes BOTH 32-row halves of its 32-col slab,
// reusing one weight fragment for 2 MFMAs -> weight L2 traffic halves vs the
// 32-row version. As/Bs alias one 32 KB LDS buffer (extra barrier between
// phase-2 reads and Bs writes). XOR swizzle (row ^ ks&7 in 16B units) keeps
// all fragment reads/writes spread across bank groups.
__global__ __launch_bounds__(512) void k_gin_layer(
    const unsigned short* __restrict__ hin, const unsigned short* __restrict__ vnb,
    const int* __restrict__ batch,
    const int* __restrict__ rowptr, const int* __restrict__ ssrc,
    const unsigned short* __restrict__ Wf1, const float* __restrict__ b1,
    const unsigned short* __restrict__ Wf2, const float* __restrict__ b2,
    const float* __restrict__ bng, const float* __restrict__ bnb,
    const float* __restrict__ bnm, const float* __restrict__ bnv,
    unsigned short* __restrict__ hout) {
  __shared__ unsigned short S[16384];  // 32 KB: As then (aliased) Bs
  int tid = threadIdx.x;
  int m0 = blockIdx.x * 64;
  int r = tid >> 3, q = tid & 7;
  int m = m0 + r;
  bool valid = (m < NN);
  float acc[32];
#pragma unroll
  for (int i = 0; i < 32; ++i) acc[i] = 0.f;

#define ACC8(off, H, V)                                \
  acc[(off) + 0] += blo((H).x) + blo((V).x);           \
  acc[(off) + 1] += bhi((H).x) + bhi((V).x);           \
  acc[(off) + 2] += blo((H).y) + blo((V).y);           \
  acc[(off) + 3] += bhi((H).y) + bhi((V).y);           \
  acc[(off) + 4] += blo((H).z) + blo((V).z);           \
  acc[(off) + 5] += bhi((H).z) + bhi((V).z);           \
  acc[(off) + 6] += blo((H).w) + blo((V).w);           \
  acc[(off) + 7] += bhi((H).w) + bhi((V).w);

  int qo = q * 16;
  if (valid) {
    int g = batch[m];
    const uint4* hp = (const uint4*)(hin + (size_t)m * DD + qo);
    const uint4* hq = (const uint4*)(hin + (size_t)m * DD + 128 + qo);
    const uint4* vp = (const uint4*)(vnb + (size_t)g * DD + qo);
    const uint4* vq = (const uint4*)(vnb + (size_t)g * DD + 128 + qo);
    uint4 h0 = hp[0], h1 = hp[1], h2 = hq[0], h3 = hq[1];
    uint4 v0 = vp[0], v1 = vp[1], v2 = vq[0], v3 = vq[1];
    ACC8(0, h0, v0) ACC8(8, h1, v1) ACC8(16, h2, v2) ACC8(24, h3, v3)
  }
  int b = valid ? rowptr[m] : 0;
  int e = valid ? rowptr[m + 1] : 0;
  for (int t = b; t < e; ++t) {
    int s = ssrc[t];
    int g = batch[s];
    const uint4* hp = (const uint4*)(hin + (size_t)s * DD + qo);
    const uint4* hq = (const uint4*)(hin + (size_t)s * DD + 128 + qo);
    const uint4* vp = (const uint4*)(vnb + (size_t)g * DD + qo);
    const uint4* vq = (const uint4*)(vnb + (size_t)g * DD + 128 + qo);
    uint4 h0 = hp[0], h1 = hp[1], h2 = hq[0], h3 = hq[1];
    uint4 v0 = vp[0], v1 = vp[1], v2 = vq[0], v3 = vq[1];
    ACC8(0, h0, v0) ACC8(8, h1, v1) ACC8(16, h2, v2) ACC8(24, h3, v3)
  }
#undef ACC8

  // pack acc -> As fragments (swizzled: row ^ (ks&7), 16B units)
#pragma unroll
  for (int cc = 0; cc < 2; ++cc) {
#pragma unroll
    for (int lh = 0; lh < 2; ++lh) {
      int ks = q + cc * 8;
      int o = cc * 16 + lh * 8;
      uint4 w;
      w.x = pack2(acc[o + 0], acc[o + 1]);
      w.y = pack2(acc[o + 2], acc[o + 3]);
      w.z = pack2(acc[o + 4], acc[o + 5]);
      w.w = pack2(acc[o + 6], acc[o + 7]);
      int a16 = ((ks * 2 + lh) << 6) | (r ^ q);
      *(uint4*)(S + (a16 << 3)) = w;
    }
  }
  __syncthreads();

  int wave = tid >> 6, lane = tid & 63;
  int lrow = lane & 31, lhi = lane >> 5;
  int c = wave * 32 + lrow;

  // ---- phase 2: hid = relu(z @ W1 + b1) ----
  floatx16 f0 = (floatx16)(0.f), f1 = (floatx16)(0.f);
  {
    const bf16x8* wf = (const bf16x8*)Wf1;
#pragma unroll
    for (int ks = 0; ks < 16; ++ks) {
      int rb = ((ks * 2 + lhi) << 6) | (lrow ^ (ks & 7));
      bf16x8 a0 = *(const bf16x8*)(S + (rb << 3));
      bf16x8 a1 = *(const bf16x8*)(S + ((rb + 32) << 3));
      bf16x8 bb = wf[((wave * 16 + ks) << 6) + lane];
      f0 = __builtin_amdgcn_mfma_f32_32x32x16_bf16(a0, bb, f0, 0, 0, 0);
      f1 = __builtin_amdgcn_mfma_f32_32x32x16_bf16(a1, bb, f1, 0, 0, 0);
    }
  }
  __syncthreads();  // all As reads done -> safe to overwrite with Bs
  {
    float shf = b1[c];
    int ks2 = c >> 4, lh2 = (c >> 3) & 1, j2 = c & 7;
    int base = (ks2 * 2 + lh2) << 6;
    int sx = ks2 & 7;
#pragma unroll
    for (int reg = 0; reg < 16; ++reg) {
      int row = (reg & 3) + ((reg >> 2) << 3) + (lhi << 2);
      S[((base | (row ^ sx)) << 3) + j2] = f2bf(fmaxf(f0[reg] + shf, 0.f));
      S[((base | ((row ^ sx) + 32)) << 3) + j2] = f2bf(fmaxf(f1[reg] + shf, 0.f));
    }
  }
  __syncthreads();

  // ---- phase 3: h = leaky0.1(bn(hid @ W2 + b2)) -> global ----
  floatx16 g0 = (floatx16)(0.f), g1 = (floatx16)(0.f);
  {
    const bf16x8* wf = (const bf16x8*)Wf2;
#pragma unroll
    for (int ks = 0; ks < 16; ++ks) {
      int rb = ((ks * 2 + lhi) << 6) | (lrow ^ (ks & 7));
      bf16x8 a0 = *(const bf16x8*)(S + (rb << 3));
      bf16x8 a1 = *(const bf16x8*)(S + ((rb + 32) << 3));
      bf16x8 bb = wf[((wave * 16 + ks) << 6) + lane];
      g0 = __builtin_amdgcn_mfma_f32_32x32x16_bf16(a0, bb, g0, 0, 0, 0);
      g1 = __builtin_amdgcn_mfma_f32_32x32x16_bf16(a1, bb, g1, 0, 0, 0);
    }
  }
  {
    float s = bng[c] * rsqrtf(bnv[c] + BN_EPS);
    float shf = b2[c] * s + bnb[c] - bnm[c] * s;
#pragma unroll
    for (int reg = 0; reg < 16; ++reg) {
      int row = (reg & 3) + ((reg >> 2) << 3) + (lhi << 2);
      float v0 = g0[reg] * s + shf;
      v0 = (v0 > 0.f) ? v0 : 0.1f * v0;
      hout[(size_t)(m0 + row) * DD + c] = f2bf(v0);  // m0+row <= 99999 always
      int m1 = m0 + 32 + row;
      if (m1 < NN) {
        float v1 = g1[reg] * s + shf;
        v1 = (v1 > 0.f) ? v1 : 0.1f * v1;
        hout[(size_t)m1 * DD + c] = f2bf(v1);
      }
    }
  }
}

// ---------------- fused vn MLP: vnb = relu(bn2(relu(bn1(t0@W1+b1))@W2+b2)) -------
__global__ __launch_bounds__(256) void k_vn_mlp(
    const unsigned short* __restrict__ t0b,
    const unsigned short* __restrict__ Wf1, const float* __restrict__ b1,
    const float* __restrict__ bn1g, const float* __restrict__ bn1b,
    const float* __restrict__ bn1m, const float* __restrict__ bn1v,
    const unsigned short* __restrict__ Wf2, const float* __restrict__ b2,
    const float* __restrict__ bn2g, const float* __restrict__ bn2b,
    const float* __restrict__ bn2m, const float* __restrict__ bn2v,
    unsigned short* __restrict__ vnb) {
  __shared__ unsigned short As[2][16][2][32][8];  // 32 KB
  __shared__ unsigned short Bs[2][16][2][32][8];  // 32 KB
  int tid = threadIdx.x;
  int m0 = blockIdx.x * 64;
#pragma unroll
  for (int i = 0; i < 8; ++i) {
    int qq = i * 256 + tid;
    int lr = qq & 31, lh = (qq >> 5) & 1, ks = (qq >> 6) & 15, wm = qq >> 10;
    int m = m0 + wm * 32 + lr;
    uint4 v = make_uint4(0u, 0u, 0u, 0u);
    if (m < NG) v = *(const uint4*)(t0b + (size_t)m * DD + ks * 16 + lh * 8);
    *(uint4*)&As[wm][ks][lh][lr][0] = v;
  }
  __syncthreads();

  int wave = tid >> 6, lane = tid & 63;
  int wm = wave & 1, nhalf = wave >> 1;
  int lrow = lane & 31, lhi = lane >> 5;

  {
    floatx16 acc[4];
#pragma unroll
    for (int j = 0; j < 4; ++j) acc[j] = (floatx16)(0.f);
    const bf16x8* wf = (const bf16x8*)Wf1;
#pragma unroll
    for (int ks = 0; ks < 16; ++ks) {
      bf16x8 a = *(const bf16x8*)&As[wm][ks][lhi][lrow][0];
#pragma unroll
      for (int j = 0; j < 4; ++j) {
        int nt = nhalf * 4 + j;
        bf16x8 b = wf[((nt * 16 + ks) << 6) + lane];
        acc[j] = __builtin_amdgcn_mfma_f32_32x32x16_bf16(a, b, acc[j], 0, 0, 0);
      }
    }
#pragma unroll
    for (int j = 0; j < 4; ++j) {
      int c = nhalf * 128 + j * 32 + lrow;
      float s = bn1g[c] * rsqrtf(bn1v[c] + BN_EPS);
      float shf = b1[c] * s + bn1b[c] - bn1m[c] * s;
      int ks2 = c >> 4, lh2 = (c >> 3) & 1, j2 = c & 7;
#pragma unroll
      for (int reg = 0; reg < 16; ++reg) {
        int row = (reg & 3) + ((reg >> 2) << 3) + (lhi << 2);
        float v = fmaxf(acc[j][reg] * s + shf, 0.f);
        Bs[wm][ks2][lh2][row][j2] = f2bf(v);
      }
    }
  }
  __syncthreads();

  {
    floatx16 acc[4];
#pragma unroll
    for (int j = 0; j < 4; ++j) acc[j] = (floatx16)(0.f);
    const bf16x8* wf = (const bf16x8*)Wf2;
#pragma unroll
    for (int ks = 0; ks < 16; ++ks) {
      bf16x8 a = *(const bf16x8*)&Bs[wm][ks][lhi][lrow][0];
#pragma unroll
      for (int j = 0; j < 4; ++j) {
        int nt = nhalf * 4 + j;
        bf16x8 b = wf[((nt * 16 + ks) << 6) + lane];
        acc[j] = __builtin_amdgcn_mfma_f32_32x32x16_bf16(a, b, acc[j], 0, 0, 0);
      }
    }
#pragma unroll
    for (int j = 0; j < 4; ++j) {
      int c = nhalf * 128 + j * 32 + lrow;
      float s = bn2g[c] * rsqrtf(bn2v[c] + BN_EPS);
      float shf = b2[c] * s + bn2b[c] - bn2m[c] * s;
#pragma unroll
      for (int reg = 0; reg < 16; ++reg) {
        int row = (reg & 3) + ((reg >> 2) << 3) + (lhi << 2);
        int m = m0 + wm * 32 + row;
        if (m < NG) {
          float v = fmaxf(acc[j][reg] * s + shf, 0.f);
          vnb[(size_t)m * DD + c] = f2bf(v);
        }
      }
    }
  }
}

// ---------------- fused head: out = relu(relu(g@W1+b1)@W2+b2)@W3+b3, all fp32 -------
__global__ __launch_bounds__(256) void k_head(
    const float* __restrict__ X,
    const float* __restrict__ w1, const float* __restrict__ b1,
    const float* __restrict__ w2, const float* __restrict__ b2,
    const float* __restrict__ w3, const float* __restrict__ b3,
    float* __restrict__ out) {
  __shared__ float Xs[32][260];
  __shared__ float Ws[8192];
  __shared__ float H1[32][132];
  __shared__ float H2[32][68];
  __shared__ float W3s[64][12];
  int tid = threadIdx.x;
  int m0 = blockIdx.x * 32;
#pragma unroll
  for (int i = 0; i < 8; ++i) {
    int p = i * 256 + tid;
    int r = p >> 6, c4 = (p & 63) << 2;
    float4 v = make_float4(0.f, 0.f, 0.f, 0.f);
    if (m0 + r < NG) v = *(const float4*)(X + (size_t)(m0 + r) * 256 + c4);
    *(float4*)&Xs[r][c4] = v;
  }
  for (int p = tid; p < 704; p += 256) W3s[p / 11][p % 11] = w3[p];

  int r0 = (tid >> 5) << 2;
  int c0 = (tid & 31) << 2;
  float a1[4][4] = {};
  for (int k0 = 0; k0 < 256; k0 += 64) {
    __syncthreads();
#pragma unroll
    for (int i = 0; i < 8; ++i) {
      int p = i * 256 + tid;
      int r = p >> 5, c4 = (p & 31) << 2;
      *(float4*)&Ws[r * 128 + c4] = *(const float4*)(w1 + (size_t)(k0 + r) * 128 + c4);
    }
    __syncthreads();
#pragma unroll 4
    for (int k = 0; k < 64; ++k) {
      float4 wv = *(float4*)&Ws[k * 128 + c0];
      float xv[4];
#pragma unroll
      for (int i = 0; i < 4; ++i) xv[i] = Xs[r0 + i][k0 + k];
#pragma unroll
      for (int i = 0; i < 4; ++i) {
        a1[i][0] = fmaf(xv[i], wv.x, a1[i][0]);
        a1[i][1] = fmaf(xv[i], wv.y, a1[i][1]);
        a1[i][2] = fmaf(xv[i], wv.z, a1[i][2]);
        a1[i][3] = fmaf(xv[i], wv.w, a1[i][3]);
      }
    }
  }
#pragma unroll
  for (int i = 0; i < 4; ++i) {
    float4 o;
    o.x = fmaxf(a1[i][0] + b1[c0 + 0], 0.f);
    o.y = fmaxf(a1[i][1] + b1[c0 + 1], 0.f);
    o.z = fmaxf(a1[i][2] + b1[c0 + 2], 0.f);
    o.w = fmaxf(a1[i][3] + b1[c0 + 3], 0.f);
    *(float4*)&H1[r0 + i][c0] = o;
  }
  __syncthreads();
#pragma unroll
  for (int i = 0; i < 8; ++i) {
    int p = i * 256 + tid;
    int r = p >> 4, c4 = (p & 15) << 2;
    *(float4*)&Ws[r * 64 + c4] = *(const float4*)(w2 + (size_t)r * 64 + c4);
  }
  __syncthreads();
  int r2 = (tid >> 4) << 1;
  int c2 = (tid & 15) << 2;
  float a2[2][4] = {};
#pragma unroll 4
  for (int k = 0; k < 128; ++k) {
    float4 wv = *(float4*)&Ws[k * 64 + c2];
    float x0 = H1[r2][k], x1 = H1[r2 + 1][k];
    a2[0][0] = fmaf(x0, wv.x, a2[0][0]);
    a2[0][1] = fmaf(x0, wv.y, a2[0][1]);
    a2[0][2] = fmaf(x0, wv.z, a2[0][2]);
    a2[0][3] = fmaf(x0, wv.w, a2[0][3]);
    a2[1][0] = fmaf(x1, wv.x, a2[1][0]);
    a2[1][1] = fmaf(x1, wv.y, a2[1][1]);
    a2[1][2] = fmaf(x1, wv.z, a2[1][2]);
    a2[1][3] = fmaf(x1, wv.w, a2[1][3]);
  }
#pragma unroll
  for (int i = 0; i < 2; ++i) {
    float4 o;
    o.x = fmaxf(a2[i][0] + b2[c2 + 0], 0.f);
    o.y = fmaxf(a2[i][1] + b2[c2 + 1], 0.f);
    o.z = fmaxf(a2[i][2] + b2[c2 + 2], 0.f);
    o.w = fmaxf(a2[i][3] + b2[c2 + 3], 0.f);
    *(float4*)&H2[r2 + i][c2] = o;
  }
  __syncthreads();
  for (int p = tid; p < 352; p += 256) {
    int r = p / 11, c = p - (p / 11) * 11;
    float acc = b3[c];
#pragma unroll 8
    for (int k = 0; k < 64; ++k) acc = fmaf(H2[r][k], W3s[k][c], acc);
    if (m0 + r < NG) out[(size_t)(m0 + r) * 11 + c] = acc;
  }
}

extern "C" void kernel_launch(void* const* d_in, const int* in_sizes, int n_in,
                              void* d_out, int out_size, void* d_ws, size_t ws_size,
                              hipStream_t stream) {
  const float* x      = (const float*)d_in[0];
  const int*   ei     = (const int*)d_in[1];
  const int*   batch  = (const int*)d_in[2];
  const float* node_w = (const float*)d_in[3];
  const float* node_b = (const float*)d_in[4];
  const float* vn_w   = (const float*)d_in[5];
  const float* gin_w1 = (const float*)d_in[6];
  const float* gin_b1 = (const float*)d_in[7];
  const float* gin_w2 = (const float*)d_in[8];
  const float* gin_b2 = (const float*)d_in[9];
  const float* bn_g   = (const float*)d_in[10];
  const float* bn_b   = (const float*)d_in[11];
  const float* bn_m   = (const float*)d_in[12];
  const float* bn_v   = (const float*)d_in[13];
  const float* vn_w1  = (const float*)d_in[14];
  const float* vn_b1  = (const float*)d_in[15];
  const float* vbn1g  = (const float*)d_in[16];
  const float* vbn1b  = (const float*)d_in[17];
  const float* vbn1m  = (const float*)d_in[18];
  const float* vbn1v  = (const float*)d_in[19];
  const float* vn_w2  = (const float*)d_in[20];
  const float* vn_b2  = (const float*)d_in[21];
  const float* vbn2g  = (const float*)d_in[22];
  const float* vbn2b  = (const float*)d_in[23];
  const float* vbn2m  = (const float*)d_in[24];
  const float* vbn2v  = (const float*)d_in[25];
  const float* head_w1 = (const float*)d_in[26];
  const float* head_b1 = (const float*)d_in[27];
  const float* head_w2 = (const float*)d_in[28];
  const float* head_b2 = (const float*)d_in[29];
  const float* head_w3 = (const float*)d_in[30];
  const float* head_b3 = (const float*)d_in[31];

  // ---- workspace layout (~110 MB) ----
  unsigned short* h16   = (unsigned short*)d_ws;          // [NN*DD] ping
  unsigned short* u16   = h16 + (size_t)NN * DD;          // [NN*DD] pong
  unsigned short* vnb   = u16 + (size_t)NN * DD;          // [NG*DD]
  unsigned short* t0b   = vnb + (size_t)NG * DD;          // [NG*DD]
  unsigned short* wf1   = t0b + (size_t)NG * DD;          // [5*65536]
  unsigned short* wf2   = wf1 + 5 * 65536;                // [5*65536]
  unsigned short* wfv1  = wf2 + 5 * 65536;                // [4*65536]
  unsigned short* wfv2  = wfv1 + 4 * 65536;               // [4*65536]
  float* t0f  = (float*)(wfv2 + 4 * 65536);               // [NG*DD]
  int* rowptr = (int*)(t0f + (size_t)NG * DD);            // [NN+1]
  int* cursor = rowptr + NN + 1;                          // [NN]
  int* gstart = cursor + NN;                              // [NG]
  int* gend   = gstart + NG;                              // [NG]
  int* ssrc   = gend + NG;                                // [NE]
  int* bsum   = ssrc + NE;                                // [128]
  int* bbase  = bsum + 128;                               // [128]

  const int* src = ei;
  const int* dst = ei + NE;

  const int NB = (NN + 1023) / 1024;  // 98

  // ---- once per launch: weight pack + vn init + CSR + graph bounds ----
  k_pack_all<<<(18 * 65536 + NG * DD + 255) / 256, 256, 0, stream>>>(
      gin_w1, gin_w2, vn_w1, vn_w2, wf1, vn_w, vnb);
  k_zeroi<<<(NN + 2 * NG + 255) / 256, 256, 0, stream>>>(cursor, NN + 2 * NG);
  k_hist<<<(NE + 255) / 256, 256, 0, stream>>>(dst, cursor);
  k_bsum<<<NB, 1024, 0, stream>>>(cursor, bsum);
  k_scanb<<<1, 128, 0, stream>>>(bsum, bbase, NB);
  k_rowptr<<<NB, 1024, 0, stream>>>(cursor, bbase, rowptr, cursor);
  k_fill_src<<<(NE + 255) / 256, 256, 0, stream>>>(src, dst, cursor, ssrc);
  k_gbounds<<<(NN + 255) / 256, 256, 0, stream>>>(batch, gstart, gend);

  unsigned short* hin = h16;
  unsigned short* hout = u16;
  k_node_encode<<<NN / 16, 256, 0, stream>>>(x, node_w, node_b, hin);

  const int GG = (NN + 63) / 64;      // 1563
  const int GM_NG = (NG + 63) / 64;   // 32

  for (int l = 0; l < NL; ++l) {
    // h_out = leaky(bn(relu(((h+vn)[m] + sum (h+vn)[src]) @ W1 + b1) @ W2 + b2))
    k_gin_layer<<<GG, 512, 0, stream>>>(
        hin, vnb, batch, rowptr, ssrc,
        wf1 + (size_t)l * 65536, gin_b1 + l * DD,
        wf2 + (size_t)l * 65536, gin_b2 + l * DD,
        bn_g + l * DD, bn_b + l * DD, bn_m + l * DD, bn_v + l * DD, hout);
    if (l < NL - 1) {
      // t0 = pool(h) + vn  (bf16), then vn = vn_mlp(t0)
      k_pool_seg<0><<<NG, 256, 0, stream>>>(hout, vnb, gstart, gend, t0b, nullptr);
      k_vn_mlp<<<GM_NG, 256, 0, stream>>>(
          t0b,
          wfv1 + (size_t)l * 65536, vn_b1 + l * DD,
          vbn1g + l * DD, vbn1b + l * DD, vbn1m + l * DD, vbn1v + l * DD,
          wfv2 + (size_t)l * 65536, vn_b2 + l * DD,
          vbn2g + l * DD, vbn2b + l * DD, vbn2m + l * DD, vbn2v + l * DD,
          vnb);
    }
    unsigned short* tmp = hin; hin = hout; hout = tmp;
  }
  // final pool (fp32, no vn) + fused head; last layer's output is in hin after swap
  k_pool_seg<1><<<NG, 256, 0, stream>>>(hin, nullptr, gstart, gend, nullptr, t0f);
  k_head<<<(NG + 31) / 32, 256, 0, stream>>>(
      t0f, head_w1, head_b1, head_w2, head_b2, head_w3, head_b3, (float*)d_out);
}

// Round 2
// 720.998 us; speedup vs baseline: 1.0258x; 1.0258x over previous
//
#include <hip/hip_runtime.h>
#include <hip/hip_bf16.h>

#define NN 100000
#define NE 300000
#define NG 2000
#define DD 256
#define NL 5
#define BN_EPS 1e-5f

typedef __bf16 bf16x8 __attribute__((ext_vector_type(8)));
typedef float floatx16 __attribute__((ext_vector_type(16)));

__device__ inline unsigned short f2bf(float x) {
  unsigned int u = __builtin_bit_cast(unsigned int, x);
  unsigned int r = u + 0x7FFFu + ((u >> 16) & 1u);
  return (unsigned short)(r >> 16);
}
__device__ inline float bf2f(unsigned short u) {
  return __builtin_bit_cast(float, (unsigned int)u << 16);
}
__device__ inline float4 bfu4(ushort4 u) {
  return make_float4(bf2f(u.x), bf2f(u.y), bf2f(u.z), bf2f(u.w));
}
__device__ inline float blo(unsigned int v) {
  return __builtin_bit_cast(float, v << 16);
}
__device__ inline float bhi(unsigned int v) {
  return __builtin_bit_cast(float, v & 0xFFFF0000u);
}
__device__ inline unsigned int pack2(float a, float b) {
  return (unsigned int)f2bf(a) | ((unsigned int)f2bf(b) << 16);
}

// ---------------- utility ----------------
__global__ __launch_bounds__(256) void k_zeroi(int* __restrict__ p, int n) {
  int i = blockIdx.x * 256 + threadIdx.x;
  if (i < n) p[i] = 0;
}

// ---------------- weight pack (18 matrices) + vn init, one dispatch ----------------
__global__ __launch_bounds__(256) void k_pack_all(
    const float* __restrict__ gw1, const float* __restrict__ gw2,
    const float* __restrict__ vw1, const float* __restrict__ vw2,
    unsigned short* __restrict__ Wf,
    const float* __restrict__ vnw, unsigned short* __restrict__ vnb) {
  int idx = blockIdx.x * 256 + threadIdx.x;
  if (idx >= 18 * 65536) {
    int i = idx - 18 * 65536;
    if (i < NG * DD) vnb[i] = f2bf(vnw[i & (DD - 1)]);
    return;
  }
  int m = idx >> 16, r = idx & 65535;
  int j = r & 7, lane = (r >> 3) & 63, ks = (r >> 9) & 15, nt = r >> 13;
  int n = nt * 32 + (lane & 31);
  int k = ks * 16 + ((lane >> 5) << 3) + j;
  const float* W;
  int mm;
  if (m < 5) { W = gw1; mm = m; }
  else if (m < 10) { W = gw2; mm = m - 5; }
  else if (m < 14) { W = vw1; mm = m - 10; }
  else { W = vw2; mm = m - 14; }
  Wf[idx] = f2bf(W[(size_t)mm * 65536 + k * 256 + n]);
}

// ---------------- CSR build ----------------
__global__ __launch_bounds__(256) void k_hist(const int* __restrict__ dst,
                                              int* __restrict__ cnt) {
  int e = blockIdx.x * 256 + threadIdx.x;
  if (e < NE) atomicAdd(&cnt[dst[e]], 1);
}

__global__ __launch_bounds__(1024) void k_bsum(const int* __restrict__ cnt,
                                               int* __restrict__ bsum) {
  __shared__ int sh[1024];
  int t = threadIdx.x, idx = blockIdx.x * 1024 + t;
  sh[t] = (idx < NN) ? cnt[idx] : 0;
  __syncthreads();
  for (int off = 512; off > 0; off >>= 1) {
    if (t < off) sh[t] += sh[t + off];
    __syncthreads();
  }
  if (t == 0) bsum[blockIdx.x] = sh[0];
}

__global__ __launch_bounds__(128) void k_scanb(const int* __restrict__ bsum,
                                               int* __restrict__ bbase, int nb) {
  __shared__ int sh[128];
  int t = threadIdx.x;
  sh[t] = (t < nb) ? bsum[t] : 0;
  __syncthreads();
  if (t == 0) {
    int run = 0;
    for (int i = 0; i < nb; ++i) { int v = sh[i]; sh[i] = run; run += v; }
  }
  __syncthreads();
  if (t < nb) bbase[t] = sh[t];
}

__global__ __launch_bounds__(1024) void k_rowptr(const int* __restrict__ cnt,
                                                 const int* __restrict__ bbase,
                                                 int* __restrict__ rowptr,
                                                 int* __restrict__ cursor) {
  __shared__ int sh[1024];
  int t = threadIdx.x, idx = blockIdx.x * 1024 + t;
  int v = (idx < NN) ? cnt[idx] : 0;
  sh[t] = v;
  __syncthreads();
  for (int off = 1; off < 1024; off <<= 1) {
    int add = (t >= off) ? sh[t - off] : 0;
    __syncthreads();
    sh[t] += add;
    __syncthreads();
  }
  if (idx < NN) {
    int excl = sh[t] - v + bbase[blockIdx.x];
    rowptr[idx] = excl;
    cursor[idx] = excl;
  }
  if (blockIdx.x == 0 && t == 0) rowptr[NN] = NE;
}

// writes (src, batch[src]) pairs so the gather loop has no dependent
// ssrc -> batch -> vn load chain
__global__ __launch_bounds__(256) void k_fill_src(const int* __restrict__ src,
                                                  const int* __restrict__ dst,
                                                  const int* __restrict__ batch,
                                                  int* __restrict__ cursor,
                                                  int2* __restrict__ ssrc2) {
  int e = blockIdx.x * 256 + threadIdx.x;
  if (e >= NE) return;
  int s = src[e];
  int pos = atomicAdd(&cursor[dst[e]], 1);
  ssrc2[pos] = make_int2(s, batch[s]);
}

// ---------------- graph bounds from sorted batch (no atomics) ----------------
__global__ __launch_bounds__(256) void k_gbounds(const int* __restrict__ batch,
                                                 int* __restrict__ gstart,
                                                 int* __restrict__ gend) {
  int n = blockIdx.x * 256 + threadIdx.x;
  if (n >= NN) return;
  int b = batch[n];
  if (n == 0 || batch[n - 1] != b) gstart[b] = n;
  if (n == NN - 1 || batch[n + 1] != b) gend[b] = n + 1;
}

// ---------------- node encode -> bf16 (16 nodes/block, w in LDS) ----------------
__global__ __launch_bounds__(256) void k_node_encode(
    const float* __restrict__ x, const float* __restrict__ w,
    const float* __restrict__ b, unsigned short* __restrict__ h16) {
  __shared__ float ws[20][256];
  __shared__ float xr[16][20];
  int tid = threadIdx.x;
  int n0 = blockIdx.x * 16;
  for (int p = tid; p < 20 * 64; p += 256) {
    int k = p >> 6, c4 = (p & 63) << 2;
    *(float4*)&ws[k][c4] = *(const float4*)(w + k * 256 + c4);
  }
  for (int p = tid; p < 320; p += 256) {
    int nn = p / 20, k = p - nn * 20;
    xr[nn][k] = x[(size_t)(n0 + nn) * 20 + k];
  }
  __syncthreads();
  int ln = tid >> 6, c4 = (tid & 63) << 2;
  float4 bv = *(const float4*)(b + c4);
  float a[4][4];
#pragma unroll
  for (int nn = 0; nn < 4; ++nn) {
    a[nn][0] = bv.x; a[nn][1] = bv.y; a[nn][2] = bv.z; a[nn][3] = bv.w;
  }
#pragma unroll
  for (int k = 0; k < 20; ++k) {
    float4 wv = *(float4*)&ws[k][c4];
#pragma unroll
    for (int nn = 0; nn < 4; ++nn) {
      float xv = xr[ln * 4 + nn][k];
      a[nn][0] = fmaf(xv, wv.x, a[nn][0]);
      a[nn][1] = fmaf(xv, wv.y, a[nn][1]);
      a[nn][2] = fmaf(xv, wv.z, a[nn][2]);
      a[nn][3] = fmaf(xv, wv.w, a[nn][3]);
    }
  }
#pragma unroll
  for (int nn = 0; nn < 4; ++nn) {
    int n = n0 + ln * 4 + nn;
    *(ushort4*)(h16 + (size_t)n * DD + c4) =
        make_ushort4(f2bf(a[nn][0]), f2bf(a[nn][1]), f2bf(a[nn][2]), f2bf(a[nn][3]));
  }
}

// ---------------- segment pool: one block per graph, no atomics ----------------
template <int MODE>
__global__ __launch_bounds__(256) void k_pool_seg(
    const unsigned short* __restrict__ h16, const unsigned short* __restrict__ vnb,
    const int* __restrict__ gstart, const int* __restrict__ gend,
    unsigned short* __restrict__ outb, float* __restrict__ outf) {
  __shared__ float4 sh[4][64];
  int g = blockIdx.x;
  int lane = threadIdx.x & 63, grp = threadIdx.x >> 6;
  int c4 = lane << 2;
  int s = gstart[g], e = gend[g];
  float4 acc = make_float4(0.f, 0.f, 0.f, 0.f);
  for (int n = s + grp; n < e; n += 4) {
    float4 v = bfu4(*(const ushort4*)(h16 + (size_t)n * DD + c4));
    acc.x += v.x; acc.y += v.y; acc.z += v.z; acc.w += v.w;
  }
  sh[grp][lane] = acc;
  __syncthreads();
  if (grp == 0) {
    float4 a0 = sh[0][lane], a1 = sh[1][lane], a2 = sh[2][lane], a3 = sh[3][lane];
    acc.x = a0.x + a1.x + a2.x + a3.x;
    acc.y = a0.y + a1.y + a2.y + a3.y;
    acc.z = a0.z + a1.z + a2.z + a3.z;
    acc.w = a0.w + a1.w + a2.w + a3.w;
    if (MODE == 0) {
      float4 v = bfu4(*(const ushort4*)(vnb + (size_t)g * DD + c4));
      acc.x += v.x; acc.y += v.y; acc.z += v.z; acc.w += v.w;
      *(ushort4*)(outb + (size_t)g * DD + c4) =
          make_ushort4(f2bf(acc.x), f2bf(acc.y), f2bf(acc.z), f2bf(acc.w));
    } else {
      *(float4*)(outf + (size_t)g * DD + c4) = acc;
    }
  }
}

// ---------------- fused GIN layer (512 threads, 32 rows/block) ----------------
// Gather: 16 threads/row, 16 cols each (round-0 parallelism), with the
// +vn[batch] add fused inline (vn table is 1 MB, L2-resident) and a 1-deep
// software pipeline: edge t+1's four 16B loads issue BEFORE the waitcnt that
// consumes edge t's data, overlapping one full load latency per iteration.
// ssrc2 carries (src, batch[src]) so there's no dependent load chain.
// LDS fragments XOR-swizzled (row ^ (ks&7), 16B units) -> conflict-free
// ds_read_b128 in the MFMA phases (proven: 5.2M -> 0.8M conflicts).
__global__ __launch_bounds__(512) void k_gin_layer(
    const unsigned short* __restrict__ hin, const unsigned short* __restrict__ vnb,
    const int2* __restrict__ ssrc2, const int* __restrict__ batch,
    const int* __restrict__ rowptr,
    const unsigned short* __restrict__ Wf1, const float* __restrict__ b1,
    const unsigned short* __restrict__ Wf2, const float* __restrict__ b2,
    const float* __restrict__ bng, const float* __restrict__ bnb,
    const float* __restrict__ bnm, const float* __restrict__ bnv,
    unsigned short* __restrict__ hout) {
  __shared__ unsigned short As[16][2][32][8];  // 16 KB, [ks][lh][row^swz][j]
  __shared__ unsigned short Bs[16][2][32][8];  // 16 KB
  int tid = threadIdx.x;
  int m0 = blockIdx.x * 32;         // 3125 * 32 = 100000 exactly
  int r = tid >> 4, q = tid & 15;   // row 0..31, 16-col chunk 0..15
  int m = m0 + r;
  int cb = q << 4;

  // self loads first (longest time to complete)
  const unsigned short* mp = hin + (size_t)m * DD + cb;
  uint4 sh0 = *(const uint4*)mp;
  uint4 sh1 = *(const uint4*)(mp + 8);
  int gm = batch[m];
  const unsigned short* mv = vnb + (size_t)gm * DD + cb;
  uint4 sv0 = *(const uint4*)mv;
  uint4 sv1 = *(const uint4*)(mv + 8);
  int b = rowptr[m], e = rowptr[m + 1];

  // edge prologue: issue edge b's loads
  uint4 ph0 = make_uint4(0, 0, 0, 0), ph1 = ph0, pv0 = ph0, pv1 = ph0;
  if (b < e) {
    int2 sp = ssrc2[b];
    const unsigned short* hp = hin + (size_t)sp.x * DD + cb;
    const unsigned short* vp = vnb + (size_t)sp.y * DD + cb;
    ph0 = *(const uint4*)hp; ph1 = *(const uint4*)(hp + 8);
    pv0 = *(const uint4*)vp; pv1 = *(const uint4*)(vp + 8);
  }

  float acc[16];
  // init acc from self + vn (their loads have had time to land)
#define SET8(off, H, V)                                \
  acc[(off) + 0] = blo((H).x) + blo((V).x);            \
  acc[(off) + 1] = bhi((H).x) + bhi((V).x);            \
  acc[(off) + 2] = blo((H).y) + blo((V).y);            \
  acc[(off) + 3] = bhi((H).y) + bhi((V).y);            \
  acc[(off) + 4] = blo((H).z) + blo((V).z);            \
  acc[(off) + 5] = bhi((H).z) + bhi((V).z);            \
  acc[(off) + 6] = blo((H).w) + blo((V).w);            \
  acc[(off) + 7] = bhi((H).w) + bhi((V).w);
#define ACC8(off, H, V)                                \
  acc[(off) + 0] += blo((H).x) + blo((V).x);           \
  acc[(off) + 1] += bhi((H).x) + bhi((V).x);           \
  acc[(off) + 2] += blo((H).y) + blo((V).y);           \
  acc[(off) + 3] += bhi((H).y) + bhi((V).y);           \
  acc[(off) + 4] += blo((H).z) + blo((V).z);           \
  acc[(off) + 5] += bhi((H).z) + bhi((V).z);           \
  acc[(off) + 6] += blo((H).w) + blo((V).w);           \
  acc[(off) + 7] += bhi((H).w) + bhi((V).w);

  SET8(0, sh0, sv0) SET8(8, sh1, sv1)

  for (int t = b; t < e; ++t) {
    // issue NEXT edge's loads before consuming current (1-deep pipeline)
    int tn = t + 1;
    int2 sp = (tn < e) ? ssrc2[tn] : make_int2(0, 0);
    const unsigned short* hp = hin + (size_t)sp.x * DD + cb;
    const unsigned short* vp = vnb + (size_t)sp.y * DD + cb;
    uint4 nh0 = *(const uint4*)hp, nh1 = *(const uint4*)(hp + 8);
    uint4 nv0 = *(const uint4*)vp, nv1 = *(const uint4*)(vp + 8);
    ACC8(0, ph0, pv0) ACC8(8, ph1, pv1)
    ph0 = nh0; ph1 = nh1; pv0 = nv0; pv1 = nv1;
  }
#undef SET8
#undef ACC8

  // pack acc -> As fragments, swizzled: thread (r,q) owns ks=q, lh=0/1
  {
    int rs = r ^ (q & 7);
#pragma unroll
    for (int lh = 0; lh < 2; ++lh) {
      int o = lh * 8;
      uint4 w;
      w.x = pack2(acc[o + 0], acc[o + 1]);
      w.y = pack2(acc[o + 2], acc[o + 3]);
      w.z = pack2(acc[o + 4], acc[o + 5]);
      w.w = pack2(acc[o + 6], acc[o + 7]);
      *(uint4*)&As[q][lh][rs][0] = w;
    }
  }
  __syncthreads();

  int wave = tid >> 6, lane = tid & 63;
  int lrow = lane & 31, lhi = lane >> 5;
  int c = wave * 32 + lrow;

  // ---- phase 2: hid = relu(z @ W1 + b1) -> Bs ----
  {
    floatx16 f0 = (floatx16)(0.f);
    const bf16x8* wf = (const bf16x8*)Wf1;
#pragma unroll
    for (int ks = 0; ks < 16; ++ks) {
      bf16x8 a = *(const bf16x8*)&As[ks][lhi][lrow ^ (ks & 7)][0];
      bf16x8 bb = wf[((wave * 16 + ks) << 6) + lane];
      f0 = __builtin_amdgcn_mfma_f32_32x32x16_bf16(a, bb, f0, 0, 0, 0);
    }
    float shf = b1[c];
    int ks2 = c >> 4, lh2 = (c >> 3) & 1, j2 = c & 7, sx2 = ks2 & 7;
#pragma unroll
    for (int reg = 0; reg < 16; ++reg) {
      int row = (reg & 3) + ((reg >> 2) << 3) + (lhi << 2);
      Bs[ks2][lh2][row ^ sx2][j2] = f2bf(fmaxf(f0[reg] + shf, 0.f));
    }
  }
  __syncthreads();

  // ---- phase 3: h = leaky0.1(bn(hid @ W2 + b2)) -> global ----
  {
    floatx16 g0 = (floatx16)(0.f);
    const bf16x8* wf = (const bf16x8*)Wf2;
#pragma unroll
    for (int ks = 0; ks < 16; ++ks) {
      bf16x8 a = *(const bf16x8*)&Bs[ks][lhi][lrow ^ (ks & 7)][0];
      bf16x8 bb = wf[((wave * 16 + ks) << 6) + lane];
      g0 = __builtin_amdgcn_mfma_f32_32x32x16_bf16(a, bb, g0, 0, 0, 0);
    }
    float s = bng[c] * rsqrtf(bnv[c] + BN_EPS);
    float shf = b2[c] * s + bnb[c] - bnm[c] * s;
#pragma unroll
    for (int reg = 0; reg < 16; ++reg) {
      int row = (reg & 3) + ((reg >> 2) << 3) + (lhi << 2);
      float v = g0[reg] * s + shf;
      v = (v > 0.f) ? v : 0.1f * v;
      hout[(size_t)(m0 + row) * DD + c] = f2bf(v);  // m0+row < NN always
    }
  }
}

// ---------------- fused vn MLP: vnb = relu(bn2(relu(bn1(t0@W1+b1))@W2+b2)) -------
__global__ __launch_bounds__(256) void k_vn_mlp(
    const unsigned short* __restrict__ t0b,
    const unsigned short* __restrict__ Wf1, const float* __restrict__ b1,
    const float* __restrict__ bn1g, const float* __restrict__ bn1b,
    const float* __restrict__ bn1m, const float* __restrict__ bn1v,
    const unsigned short* __restrict__ Wf2, const float* __restrict__ b2,
    const float* __restrict__ bn2g, const float* __restrict__ bn2b,
    const float* __restrict__ bn2m, const float* __restrict__ bn2v,
    unsigned short* __restrict__ vnb) {
  __shared__ unsigned short As[2][16][2][32][8];  // 32 KB
  __shared__ unsigned short Bs[2][16][2][32][8];  // 32 KB
  int tid = threadIdx.x;
  int m0 = blockIdx.x * 64;
#pragma unroll
  for (int i = 0; i < 8; ++i) {
    int qq = i * 256 + tid;
    int lr = qq & 31, lh = (qq >> 5) & 1, ks = (qq >> 6) & 15, wm = qq >> 10;
    int m = m0 + wm * 32 + lr;
    uint4 v = make_uint4(0u, 0u, 0u, 0u);
    if (m < NG) v = *(const uint4*)(t0b + (size_t)m * DD + ks * 16 + lh * 8);
    *(uint4*)&As[wm][ks][lh][lr][0] = v;
  }
  __syncthreads();

  int wave = tid >> 6, lane = tid & 63;
  int wm = wave & 1, nhalf = wave >> 1;
  int lrow = lane & 31, lhi = lane >> 5;

  {
    floatx16 acc[4];
#pragma unroll
    for (int j = 0; j < 4; ++j) acc[j] = (floatx16)(0.f);
    const bf16x8* wf = (const bf16x8*)Wf1;
#pragma unroll
    for (int ks = 0; ks < 16; ++ks) {
      bf16x8 a = *(const bf16x8*)&As[wm][ks][lhi][lrow][0];
#pragma unroll
      for (int j = 0; j < 4; ++j) {
        int nt = nhalf * 4 + j;
        bf16x8 b = wf[((nt * 16 + ks) << 6) + lane];
        acc[j] = __builtin_amdgcn_mfma_f32_32x32x16_bf16(a, b, acc[j], 0, 0, 0);
      }
    }
#pragma unroll
    for (int j = 0; j < 4; ++j) {
      int c = nhalf * 128 + j * 32 + lrow;
      float s = bn1g[c] * rsqrtf(bn1v[c] + BN_EPS);
      float shf = b1[c] * s + bn1b[c] - bn1m[c] * s;
      int ks2 = c >> 4, lh2 = (c >> 3) & 1, j2 = c & 7;
#pragma unroll
      for (int reg = 0; reg < 16; ++reg) {
        int row = (reg & 3) + ((reg >> 2) << 3) + (lhi << 2);
        float v = fmaxf(acc[j][reg] * s + shf, 0.f);
        Bs[wm][ks2][lh2][row][j2] = f2bf(v);
      }
    }
  }
  __syncthreads();

  {
    floatx16 acc[4];
#pragma unroll
    for (int j = 0; j < 4; ++j) acc[j] = (floatx16)(0.f);
    const bf16x8* wf = (const bf16x8*)Wf2;
#pragma unroll
    for (int ks = 0; ks < 16; ++ks) {
      bf16x8 a = *(const bf16x8*)&Bs[wm][ks][lhi][lrow][0];
#pragma unroll
      for (int j = 0; j < 4; ++j) {
        int nt = nhalf * 4 + j;
        bf16x8 b = wf[((nt * 16 + ks) << 6) + lane];
        acc[j] = __builtin_amdgcn_mfma_f32_32x32x16_bf16(a, b, acc[j], 0, 0, 0);
      }
    }
#pragma unroll
    for (int j = 0; j < 4; ++j) {
      int c = nhalf * 128 + j * 32 + lrow;
      float s = bn2g[c] * rsqrtf(bn2v[c] + BN_EPS);
      float shf = b2[c] * s + bn2b[c] - bn2m[c] * s;
#pragma unroll
      for (int reg = 0; reg < 16; ++reg) {
        int row = (reg & 3) + ((reg >> 2) << 3) + (lhi << 2);
        int m = m0 + wm * 32 + row;
        if (m < NG) {
          float v = fmaxf(acc[j][reg] * s + shf, 0.f);
          vnb[(size_t)m * DD + c] = f2bf(v);
        }
      }
    }
  }
}

// ---------------- fused head: out = relu(relu(g@W1+b1)@W2+b2)@W3+b3, all fp32 -------
__global__ __launch_bounds__(256) void k_head(
    const float* __restrict__ X,
    const float* __restrict__ w1, const float* __restrict__ b1,
    const float* __restrict__ w2, const float* __restrict__ b2,
    const float* __restrict__ w3, const float* __restrict__ b3,
    float* __restrict__ out) {
  __shared__ float Xs[32][260];
  __shared__ float Ws[8192];
  __shared__ float H1[32][132];
  __shared__ float H2[32][68];
  __shared__ float W3s[64][12];
  int tid = threadIdx.x;
  int m0 = blockIdx.x * 32;
#pragma unroll
  for (int i = 0; i < 8; ++i) {
    int p = i * 256 + tid;
    int r = p >> 6, c4 = (p & 63) << 2;
    float4 v = make_float4(0.f, 0.f, 0.f, 0.f);
    if (m0 + r < NG) v = *(const float4*)(X + (size_t)(m0 + r) * 256 + c4);
    *(float4*)&Xs[r][c4] = v;
  }
  for (int p = tid; p < 704; p += 256) W3s[p / 11][p % 11] = w3[p];

  int r0 = (tid >> 5) << 2;
  int c0 = (tid & 31) << 2;
  float a1[4][4] = {};
  for (int k0 = 0; k0 < 256; k0 += 64) {
    __syncthreads();
#pragma unroll
    for (int i = 0; i < 8; ++i) {
      int p = i * 256 + tid;
      int r = p >> 5, c4 = (p & 31) << 2;
      *(float4*)&Ws[r * 128 + c4] = *(const float4*)(w1 + (size_t)(k0 + r) * 128 + c4);
    }
    __syncthreads();
#pragma unroll 4
    for (int k = 0; k < 64; ++k) {
      float4 wv = *(float4*)&Ws[k * 128 + c0];
      float xv[4];
#pragma unroll
      for (int i = 0; i < 4; ++i) xv[i] = Xs[r0 + i][k0 + k];
#pragma unroll
      for (int i = 0; i < 4; ++i) {
        a1[i][0] = fmaf(xv[i], wv.x, a1[i][0]);
        a1[i][1] = fmaf(xv[i], wv.y, a1[i][1]);
        a1[i][2] = fmaf(xv[i], wv.z, a1[i][2]);
        a1[i][3] = fmaf(xv[i], wv.w, a1[i][3]);
      }
    }
  }
#pragma unroll
  for (int i = 0; i < 4; ++i) {
    float4 o;
    o.x = fmaxf(a1[i][0] + b1[c0 + 0], 0.f);
    o.y = fmaxf(a1[i][1] + b1[c0 + 1], 0.f);
    o.z = fmaxf(a1[i][2] + b1[c0 + 2], 0.f);
    o.w = fmaxf(a1[i][3] + b1[c0 + 3], 0.f);
    *(float4*)&H1[r0 + i][c0] = o;
  }
  __syncthreads();
#pragma unroll
  for (int i = 0; i < 8; ++i) {
    int p = i * 256 + tid;
    int r = p >> 4, c4 = (p & 15) << 2;
    *(float4*)&Ws[r * 64 + c4] = *(const float4*)(w2 + (size_t)r * 64 + c4);
  }
  __syncthreads();
  int r2 = (tid >> 4) << 1;
  int c2 = (tid & 15) << 2;
  float a2[2][4] = {};
#pragma unroll 4
  for (int k = 0; k < 128; ++k) {
    float4 wv = *(float4*)&Ws[k * 64 + c2];
    float x0 = H1[r2][k], x1 = H1[r2 + 1][k];
    a2[0][0] = fmaf(x0, wv.x, a2[0][0]);
    a2[0][1] = fmaf(x0, wv.y, a2[0][1]);
    a2[0][2] = fmaf(x0, wv.z, a2[0][2]);
    a2[0][3] = fmaf(x0, wv.w, a2[0][3]);
    a2[1][0] = fmaf(x1, wv.x, a2[1][0]);
    a2[1][1] = fmaf(x1, wv.y, a2[1][1]);
    a2[1][2] = fmaf(x1, wv.z, a2[1][2]);
    a2[1][3] = fmaf(x1, wv.w, a2[1][3]);
  }
#pragma unroll
  for (int i = 0; i < 2; ++i) {
    float4 o;
    o.x = fmaxf(a2[i][0] + b2[c2 + 0], 0.f);
    o.y = fmaxf(a2[i][1] + b2[c2 + 1], 0.f);
    o.z = fmaxf(a2[i][2] + b2[c2 + 2], 0.f);
    o.w = fmaxf(a2[i][3] + b2[c2 + 3], 0.f);
    *(float4*)&H2[r2 + i][c2] = o;
  }
  __syncthreads();
  for (int p = tid; p < 352; p += 256) {
    int r = p / 11, c = p - (p / 11) * 11;
    float acc = b3[c];
#pragma unroll 8
    for (int k = 0; k < 64; ++k) acc = fmaf(H2[r][k], W3s[k][c], acc);
    if (m0 + r < NG) out[(size_t)(m0 + r) * 11 + c] = acc;
  }
}

extern "C" void kernel_launch(void* const* d_in, const int* in_sizes, int n_in,
                              void* d_out, int out_size, void* d_ws, size_t ws_size,
                              hipStream_t stream) {
  const float* x      = (const float*)d_in[0];
  const int*   ei     = (const int*)d_in[1];
  const int*   batch  = (const int*)d_in[2];
  const float* node_w = (const float*)d_in[3];
  const float* node_b = (const float*)d_in[4];
  const float* vn_w   = (const float*)d_in[5];
  const float* gin_w1 = (const float*)d_in[6];
  const float* gin_b1 = (const float*)d_in[7];
  const float* gin_w2 = (const float*)d_in[8];
  const float* gin_b2 = (const float*)d_in[9];
  const float* bn_g   = (const float*)d_in[10];
  const float* bn_b   = (const float*)d_in[11];
  const float* bn_m   = (const float*)d_in[12];
  const float* bn_v   = (const float*)d_in[13];
  const float* vn_w1  = (const float*)d_in[14];
  const float* vn_b1  = (const float*)d_in[15];
  const float* vbn1g  = (const float*)d_in[16];
  const float* vbn1b  = (const float*)d_in[17];
  const float* vbn1m  = (const float*)d_in[18];
  const float* vbn1v  = (const float*)d_in[19];
  const float* vn_w2  = (const float*)d_in[20];
  const float* vn_b2  = (const float*)d_in[21];
  const float* vbn2g  = (const float*)d_in[22];
  const float* vbn2b  = (const float*)d_in[23];
  const float* vbn2m  = (const float*)d_in[24];
  const float* vbn2v  = (const float*)d_in[25];
  const float* head_w1 = (const float*)d_in[26];
  const float* head_b1 = (const float*)d_in[27];
  const float* head_w2 = (const float*)d_in[28];
  const float* head_b2 = (const float*)d_in[29];
  const float* head_w3 = (const float*)d_in[30];
  const float* head_b3 = (const float*)d_in[31];

  // ---- workspace layout (~112 MB) ----
  unsigned short* h16   = (unsigned short*)d_ws;          // [NN*DD] ping
  unsigned short* u16   = h16 + (size_t)NN * DD;          // [NN*DD] pong
  unsigned short* vnb   = u16 + (size_t)NN * DD;          // [NG*DD]
  unsigned short* t0b   = vnb + (size_t)NG * DD;          // [NG*DD]
  unsigned short* wf1   = t0b + (size_t)NG * DD;          // [5*65536]
  unsigned short* wf2   = wf1 + 5 * 65536;                // [5*65536]
  unsigned short* wfv1  = wf2 + 5 * 65536;                // [4*65536]
  unsigned short* wfv2  = wfv1 + 4 * 65536;               // [4*65536]
  float* t0f   = (float*)(wfv2 + 4 * 65536);              // [NG*DD]
  int2* ssrc2  = (int2*)(t0f + (size_t)NG * DD);          // [NE] (8B aligned)
  int* rowptr  = (int*)(ssrc2 + NE);                      // [NN+1]
  int* cursor  = rowptr + NN + 1;                         // [NN]
  int* gstart  = cursor + NN;                             // [NG]
  int* gend    = gstart + NG;                             // [NG]
  int* bsum    = gend + NG;                               // [128]
  int* bbase   = bsum + 128;                              // [128]

  const int* src = ei;
  const int* dst = ei + NE;

  const int NB = (NN + 1023) / 1024;  // 98

  // ---- once per launch: weight pack + vn init + CSR + graph bounds ----
  k_pack_all<<<(18 * 65536 + NG * DD + 255) / 256, 256, 0, stream>>>(
      gin_w1, gin_w2, vn_w1, vn_w2, wf1, vn_w, vnb);
  k_zeroi<<<(NN + 2 * NG + 255) / 256, 256, 0, stream>>>(cursor, NN + 2 * NG);
  k_hist<<<(NE + 255) / 256, 256, 0, stream>>>(dst, cursor);
  k_bsum<<<NB, 1024, 0, stream>>>(cursor, bsum);
  k_scanb<<<1, 128, 0, stream>>>(bsum, bbase, NB);
  k_rowptr<<<NB, 1024, 0, stream>>>(cursor, bbase, rowptr, cursor);
  k_fill_src<<<(NE + 255) / 256, 256, 0, stream>>>(src, dst, batch, cursor, ssrc2);
  k_gbounds<<<(NN + 255) / 256, 256, 0, stream>>>(batch, gstart, gend);

  unsigned short* hin = h16;
  unsigned short* hout = u16;
  k_node_encode<<<NN / 16, 256, 0, stream>>>(x, node_w, node_b, hin);

  const int GG = NN / 32;             // 3125
  const int GM_NG = (NG + 63) / 64;   // 32

  for (int l = 0; l < NL; ++l) {
    // h_out = leaky(bn(relu(((h+vn)[m] + sum (h+vn)[src]) @ W1 + b1) @ W2 + b2))
    k_gin_layer<<<GG, 512, 0, stream>>>(
        hin, vnb, ssrc2, batch, rowptr,
        wf1 + (size_t)l * 65536, gin_b1 + l * DD,
        wf2 + (size_t)l * 65536, gin_b2 + l * DD,
        bn_g + l * DD, bn_b + l * DD, bn_m + l * DD, bn_v + l * DD, hout);
    if (l < NL - 1) {
      // t0 = pool(h) + vn  (bf16), then vn = vn_mlp(t0)
      k_pool_seg<0><<<NG, 256, 0, stream>>>(hout, vnb, gstart, gend, t0b, nullptr);
      k_vn_mlp<<<GM_NG, 256, 0, stream>>>(
          t0b,
          wfv1 + (size_t)l * 65536, vn_b1 + l * DD,
          vbn1g + l * DD, vbn1b + l * DD, vbn1m + l * DD, vbn1v + l * DD,
          wfv2 + (size_t)l * 65536, vn_b2 + l * DD,
          vbn2g + l * DD, vbn2b + l * DD, vbn2m + l * DD, vbn2v + l * DD,
          vnb);
    }
    unsigned short* tmp = hin; hin = hout; hout = tmp;
  }
  // final pool (fp32, no vn) + fused head; last layer's output is in hin after swap
  k_pool_seg<1><<<NG, 256, 0, stream>>>(hin, nullptr, gstart, gend, nullptr, t0f);
  k_head<<<(NG + 31) / 32, 256, 0, stream>>>(
      t0f, head_w1, head_b1, head_w2, head_b2, head_w3, head_b3, (float*)d_out);
}